// Round 13
// baseline (1260.561 us; speedup 1.0000x reference)
//
#include <hip/hip_runtime.h>
#include <hip/hip_cooperative_groups.h>

namespace cg = cooperative_groups;

#define NN 50000
#define EE 600000
#define DD 128
#define GG 256
#define LL 5
#define OO 10
#define BN_EPS 1e-5f
#define CPAD 513      // 512 combos + 1 sentinel (-1e30) row per layer
#define ESTRIDE 40    // fixed CSR slots per node (P(deg>40)~1e-9 at lambda=12)
#define SENT (512u << 16)
#define NT 256

// prep virtual-block ranges
#define B_SCAT  2344                       // ceil(EE/256)
#define B_CVT   3125                       // NN*DD/8 / 256
#define B_COMBO 1283                       // ceil(LL*CPAD*DD / 256)
#define B_WT    160                        // 10 mats x 16 (32x32) tiles
#define B_INV   1
#define B_POOL0 391                        // ceil(NN/128)
#define B_PREP  (B_SCAT + B_CVT + B_COMBO + B_WT + B_INV + B_POOL0)

#define AGGR_GRP ((NN + 3) / 4)            // 12500
#define CONV_TILES ((NN + 63) / 64)        // 782
#define ZWORDS ((NN * 4 + (LL + 1) * GG * DD * 4) / 16)   // uint4 count (epos|pooled)

typedef __attribute__((ext_vector_type(8))) short short8;
typedef __attribute__((ext_vector_type(16))) float float16;

// LDS: union prep-phase scratch with the conv A-tile -> 17.7 KB total
struct SmemT {
    union {
        short As[64 * 136];                          // 17408 B (dominant)
        float tile[32][33];
        int   sg[GG + 1];
        struct { int sb[128]; float part[4][DD]; } p0;
        float hpart[LL + 1][OO];
    } u;
    int sbg[64];
};

__device__ __forceinline__ unsigned short f2b(float f) {   // fp32 -> bf16 RNE
    unsigned u = __float_as_uint(f);
    unsigned r = u + 0x7FFFu + ((u >> 16) & 1u);
    return (unsigned short)(r >> 16);
}
__device__ __forceinline__ unsigned pk2(float lo, float hi) {
    return (unsigned)f2b(lo) | ((unsigned)f2b(hi) << 16);
}
__device__ __forceinline__ float blo(unsigned u) { return __uint_as_float(u << 16); }
__device__ __forceinline__ float bhi(unsigned u) { return __uint_as_float(u & 0xFFFF0000u); }

// ---------------- prep virtual block ----------------
__device__ __forceinline__ void prep_vb(
        int vb, int tid, SmemT& sm,
        const float* __restrict__ x, const int* __restrict__ ei,
        const int* __restrict__ eattr, const int* __restrict__ batch,
        const float* __restrict__ bond,
        const float* __restrict__ w1f, const float* __restrict__ w2f,
        unsigned* __restrict__ xb4, unsigned short* __restrict__ combo,
        short* __restrict__ wt, int* __restrict__ epos,
        unsigned* __restrict__ e_info, float* __restrict__ inv,
        float* __restrict__ pooled0) {
    if (vb < B_SCAT) {
        int e = vb * NT + tid;
        if (e < EE) {
            int dst = ei[EE + e];
            int slot = atomicAdd(&epos[dst], 1);
            if (slot < ESTRIDE) {
                unsigned cidx = (unsigned)eattr[e * 3 + 0] | ((unsigned)eattr[e * 3 + 1] << 3)
                              | ((unsigned)eattr[e * 3 + 2] << 6);
                e_info[dst * ESTRIDE + slot] = (unsigned)ei[e] | (cidx << 16);
            }
        }
        return;
    }
    int ob = vb - B_SCAT;
    if (ob < B_CVT) {
        int gid = ob * NT + tid;
        const float4* xp = (const float4*)(x + (size_t)gid * 8);
        float4 a = xp[0], b = xp[1];
        uint4 o;
        o.x = pk2(a.x, a.y); o.y = pk2(a.z, a.w);
        o.z = pk2(b.x, b.y); o.w = pk2(b.z, b.w);
        ((uint4*)xb4)[gid] = o;
    } else if (ob < B_CVT + B_COMBO) {
        int e = (ob - B_CVT) * NT + tid;
        if (e < LL * CPAD * DD) {
            int l = e / (CPAD * DD), rem = e - l * (CPAD * DD);
            int c = rem / DD, d = rem - c * DD;
            float s;
            if (c == 512) s = -1e30f;                 // sentinel row: relu(x+s)==0
            else {
                const float* b_ = bond + (size_t)l * 3 * 8 * DD;
                s = b_[(c & 7) * DD + d] + b_[(8 + ((c >> 3) & 7)) * DD + d]
                  + b_[(16 + (c >> 6)) * DD + d];
            }
            combo[e] = f2b(s);
        }
    } else if (ob < B_CVT + B_COMBO + B_WT) {
        // coalesced transpose: wt[mat][c][k] = bf16(W[mat][k][c])
        int b = ob - B_CVT - B_COMBO;
        int mat = b >> 4, tl = b & 15;
        int k0 = (tl >> 2) * 32, c0 = (tl & 3) * 32;
        const float* W = (mat < 5) ? (w1f + (size_t)mat * DD * DD)
                                   : (w2f + (size_t)(mat - 5) * DD * DD);
        int j = tid & 31, q = tid >> 5;
#pragma unroll
        for (int rr = 0; rr < 4; ++rr) {
            int row = q + rr * 8;
            sm.u.tile[row][j] = W[(size_t)(k0 + row) * DD + c0 + j];
        }
        __syncthreads();
#pragma unroll
        for (int rr = 0; rr < 4; ++rr) {
            int cr = q + rr * 8;
            wt[(size_t)mat * DD * DD + (size_t)(c0 + cr) * DD + k0 + j]
                = (short)f2b(sm.u.tile[j][cr]);
        }
    } else if (ob < B_CVT + B_COMBO + B_WT + B_INV) {
        int g = tid, lo = 0, hi = NN;
        while (lo < hi) { int m = (lo + hi) >> 1; if (batch[m] < g) lo = m + 1; else hi = m; }
        sm.u.sg[g] = lo;
        if (g == 0) sm.u.sg[GG] = NN;
        __syncthreads();
        inv[g] = 1.0f / fmaxf((float)(sm.u.sg[g + 1] - sm.u.sg[g]), 1.0f);
    } else {
        // layer-0 pooling of raw fp32 x: 128 nodes/block
        int b = ob - (B_CVT + B_COMBO + B_WT + B_INV);
        int n0 = b * 128;
        if (tid < 128) { int row = n0 + tid; sm.u.p0.sb[tid] = (row < NN) ? batch[row] : -1; }
        ((float*)sm.u.p0.part)[tid] = 0.f;
        ((float*)sm.u.p0.part)[tid + 256] = 0.f;
        __syncthreads();
        int gmin = sm.u.p0.sb[0];
        int col = tid & 127, rh = tid >> 7;
        float pg[4] = {0.f, 0.f, 0.f, 0.f};
        for (int r = rh; r < 128; r += 2) {
            int s = sm.u.p0.sb[r];
            float v = (s >= 0) ? x[(size_t)(n0 + r) * DD + col] : 0.f;
            int dg = s - gmin;
#pragma unroll
            for (int jj = 0; jj < 4; ++jj) pg[jj] += (dg == jj) ? v : 0.f;
        }
#pragma unroll
        for (int jj = 0; jj < 4; ++jj)
            if (pg[jj] != 0.f) atomicAdd(&sm.u.p0.part[jj][col], pg[jj]);
        __syncthreads();
        for (int q2 = tid; q2 < 4 * DD; q2 += NT) {
            int jj = q2 >> 7, c2 = q2 & 127;
            float v = sm.u.p0.part[jj][c2];
            if (v != 0.f && gmin + jj < GG) atomicAdd(&pooled0[(gmin + jj) * DD + c2], v);
        }
    }
}

// ---------------- aggregation group (4 nodes, 1 wave each) ----------------
__device__ __forceinline__ void aggr_grp(
        int grp, int tid,
        const unsigned short* __restrict__ xb, const int* __restrict__ epos,
        const unsigned* __restrict__ e_info, const unsigned short* __restrict__ cmb,
        unsigned short* __restrict__ hin) {
    int node = grp * 4 + (tid >> 6);
    int lane = tid & 63;
    if (node >= NN) return;
    const int base = node * ESTRIDE;
    int deg = epos[node]; if (deg > ESTRIDE) deg = ESTRIDE;
    const int dend = base + deg;
    const int pe   = base + ((deg + 7) & ~7);
    const int eg   = lane >> 4;
    const int f    = (lane & 15) * 8;
    float acc[8];
#pragma unroll
    for (int i = 0; i < 8; ++i) acc[i] = 0.f;
    for (int p = base; p < pe; p += 8) {
        unsigned i0 = e_info[p + eg];
        unsigned i1 = e_info[p + 4 + eg];
        if (p + eg >= dend)     i0 = SENT;
        if (p + 4 + eg >= dend) i1 = SENT;
        uint4 xv0 = *(const uint4*)&xb[(size_t)(i0 & 0xFFFFu) * DD + f];
        uint4 cv0 = *(const uint4*)&cmb[(size_t)(i0 >> 16) * DD + f];
        uint4 xv1 = *(const uint4*)&xb[(size_t)(i1 & 0xFFFFu) * DD + f];
        uint4 cv1 = *(const uint4*)&cmb[(size_t)(i1 >> 16) * DD + f];
        acc[0] += fmaxf(blo(xv0.x) + blo(cv0.x), 0.f) + fmaxf(blo(xv1.x) + blo(cv1.x), 0.f);
        acc[1] += fmaxf(bhi(xv0.x) + bhi(cv0.x), 0.f) + fmaxf(bhi(xv1.x) + bhi(cv1.x), 0.f);
        acc[2] += fmaxf(blo(xv0.y) + blo(cv0.y), 0.f) + fmaxf(blo(xv1.y) + blo(cv1.y), 0.f);
        acc[3] += fmaxf(bhi(xv0.y) + bhi(cv0.y), 0.f) + fmaxf(bhi(xv1.y) + bhi(cv1.y), 0.f);
        acc[4] += fmaxf(blo(xv0.z) + blo(cv0.z), 0.f) + fmaxf(blo(xv1.z) + blo(cv1.z), 0.f);
        acc[5] += fmaxf(bhi(xv0.z) + bhi(cv0.z), 0.f) + fmaxf(bhi(xv1.z) + bhi(cv1.z), 0.f);
        acc[6] += fmaxf(blo(xv0.w) + blo(cv0.w), 0.f) + fmaxf(blo(xv1.w) + blo(cv1.w), 0.f);
        acc[7] += fmaxf(bhi(xv0.w) + bhi(cv0.w), 0.f) + fmaxf(bhi(xv1.w) + bhi(cv1.w), 0.f);
    }
#pragma unroll
    for (int i = 0; i < 8; ++i) {
        acc[i] += __shfl_xor(acc[i], 16, 64);
        acc[i] += __shfl_xor(acc[i], 32, 64);
    }
    if (lane < 16) {
        uint4 self = *(const uint4*)&xb[(size_t)node * DD + f];
        uint4 o;
        o.x = pk2(acc[0] + blo(self.x), acc[1] + bhi(self.x));
        o.y = pk2(acc[2] + blo(self.y), acc[3] + bhi(self.y));
        o.z = pk2(acc[4] + blo(self.z), acc[5] + bhi(self.z));
        o.w = pk2(acc[6] + blo(self.w), acc[7] + bhi(self.w));
        *(uint4*)&hin[(size_t)node * DD + f] = o;
    }
}

// ---------------- one conv tile (64 rows): MFMA1->BN->MFMA2->BN + pooled partials ----------------
__device__ __forceinline__ void conv_tile(
        int tl, int tid, SmemT& sm,
        const unsigned short* __restrict__ hin,
        const short* __restrict__ Wt1, const short* __restrict__ Wt2,
        float sc1, float sh1, float sc2, float sh2,
        const int* __restrict__ batch, unsigned short* __restrict__ outb,
        float* __restrict__ pool_slot) {
    const int lane  = tid & 63;
    const int wave  = tid >> 6;
    const int col   = wave * 32 + (lane & 31);
    const int khalf = (lane >> 5) * 8;
    const int arow  = lane & 31;
    const int rbase = 4 * (lane >> 5);
    const int row0  = tl * 64;
    const int gmin  = batch[row0];

    short8 bf[8];
#pragma unroll
    for (int ch = 0; ch < 8; ++ch)
        bf[ch] = *(const short8*)&Wt1[col * DD + ch * 16 + khalf];
    if (tid < 64) {
        int row = row0 + tid;
        sm.sbg[tid] = (row < NN) ? batch[row] - gmin : -1;
    }
    for (int i = tid; i < 1024; i += NT) {
        int r = i >> 4, c8 = (i & 15) * 8;
        int row = row0 + r;
        uint4 z = make_uint4(0, 0, 0, 0);
        if (row < NN) z = *(const uint4*)&hin[(size_t)row * DD + c8];
        *(uint4*)&sm.u.As[r * 136 + c8] = z;
    }
    __syncthreads();

    float16 acc0 = {0.f,0.f,0.f,0.f,0.f,0.f,0.f,0.f,0.f,0.f,0.f,0.f,0.f,0.f,0.f,0.f};
    float16 acc1 = acc0;
#pragma unroll
    for (int ch = 0; ch < 8; ++ch) {
        short8 a0 = *(const short8*)&sm.u.As[(arow     ) * 136 + ch * 16 + khalf];
        short8 a1 = *(const short8*)&sm.u.As[(32 + arow) * 136 + ch * 16 + khalf];
        acc0 = __builtin_amdgcn_mfma_f32_32x32x16_bf16(a0, bf[ch], acc0, 0, 0, 0);
        acc1 = __builtin_amdgcn_mfma_f32_32x32x16_bf16(a1, bf[ch], acc1, 0, 0, 0);
    }
#pragma unroll
    for (int ch = 0; ch < 8; ++ch)
        bf[ch] = *(const short8*)&Wt2[col * DD + ch * 16 + khalf];
    __syncthreads();
#pragma unroll
    for (int r = 0; r < 16; ++r) {
        int rl = (r & 3) + 8 * (r >> 2) + rbase;
        sm.u.As[rl * 136 + col]        = (short)f2b(fmaxf(fmaf(acc0[r], sc1, sh1), 0.f));
        sm.u.As[(32 + rl) * 136 + col] = (short)f2b(fmaxf(fmaf(acc1[r], sc1, sh1), 0.f));
    }
    __syncthreads();
    acc0 = acc1 = float16{0.f,0.f,0.f,0.f,0.f,0.f,0.f,0.f,0.f,0.f,0.f,0.f,0.f,0.f,0.f,0.f};
#pragma unroll
    for (int ch = 0; ch < 8; ++ch) {
        short8 a0 = *(const short8*)&sm.u.As[(arow     ) * 136 + ch * 16 + khalf];
        short8 a1 = *(const short8*)&sm.u.As[(32 + arow) * 136 + ch * 16 + khalf];
        acc0 = __builtin_amdgcn_mfma_f32_32x32x16_bf16(a0, bf[ch], acc0, 0, 0, 0);
        acc1 = __builtin_amdgcn_mfma_f32_32x32x16_bf16(a1, bf[ch], acc1, 0, 0, 0);
    }
    float pg0 = 0.f, pg1 = 0.f, pg2 = 0.f, pg3 = 0.f;
#pragma unroll
    for (int r = 0; r < 16; ++r) {
        int rl  = (r & 3) + 8 * (r >> 2) + rbase;
        int row = row0 + rl;
        float v0 = fmaxf(fmaf(acc0[r], sc2, sh2), 0.f);
        float v1_ = fmaxf(fmaf(acc1[r], sc2, sh2), 0.f);
        if (row < NN)      outb[(size_t)row * DD + col]        = f2b(v0);
        if (row + 32 < NN) outb[(size_t)(row + 32) * DD + col] = f2b(v1_);
        int ga = sm.sbg[rl], gb = sm.sbg[rl + 32];
        pg0 += ((ga == 0) ? v0 : 0.f) + ((gb == 0) ? v1_ : 0.f);
        pg1 += ((ga == 1) ? v0 : 0.f) + ((gb == 1) ? v1_ : 0.f);
        pg2 += ((ga == 2) ? v0 : 0.f) + ((gb == 2) ? v1_ : 0.f);
        pg3 += ((ga == 3) ? v0 : 0.f) + ((gb == 3) ? v1_ : 0.f);
    }
    pg0 += __shfl_down(pg0, 32);
    pg1 += __shfl_down(pg1, 32);
    pg2 += __shfl_down(pg2, 32);
    pg3 += __shfl_down(pg3, 32);
    if (lane < 32) {
        if (pg0 != 0.f)                  atomicAdd(&pool_slot[(gmin    ) * DD + col], pg0);
        if (pg1 != 0.f && gmin + 1 < GG) atomicAdd(&pool_slot[(gmin + 1) * DD + col], pg1);
        if (pg2 != 0.f && gmin + 2 < GG) atomicAdd(&pool_slot[(gmin + 2) * DD + col], pg2);
        if (pg3 != 0.f && gmin + 3 < GG) atomicAdd(&pool_slot[(gmin + 3) * DD + col], pg3);
    }
    __syncthreads();   // LDS reuse guard for grid-stride callers
}

// ---------------- head block ----------------
__device__ __forceinline__ void head_blk(
        int g, int tid, SmemT& sm,
        const float* __restrict__ pooled, const float* __restrict__ inv,
        const float* __restrict__ fcw, const float* __restrict__ fcb,
        float* __restrict__ out) {
    if (tid < (LL + 1) * OO) {
        int l = tid / OO, o2 = tid - l * OO;
        const float* p = pooled + ((size_t)l * GG + g) * DD;
        const float* w = fcw + (size_t)l * DD * OO + o2;
        float s = 0.f;
        for (int d2 = 0; d2 < DD; ++d2) s = fmaf(p[d2], w[(size_t)d2 * OO], s);
        sm.u.hpart[l][o2] = s;
    }
    __syncthreads();
    if (tid < OO) {
        float sp = 0.f, sb2 = 0.f;
#pragma unroll
        for (int l = 0; l < LL + 1; ++l) { sp += sm.u.hpart[l][tid]; sb2 += fcb[l * OO + tid]; }
        out[g * OO + tid] = sp * inv[g] + sb2;
    }
}

// ===================== cooperative all-in-one =====================
__launch_bounds__(NT, 4)
__global__ void gnn_all(const float* x, const int* ei, const int* eattr, const int* batch,
                        const float* bond, const float* w1f, const float* w2f,
                        const float* cb1, const float* cg1, const float* cbe1,
                        const float* cm1, const float* cv1,
                        const float* cb2, const float* cg2, const float* cbe2,
                        const float* cm2, const float* cv2,
                        const float* fcw, const float* fcb, float* out,
                        unsigned short* xb, unsigned short* hin,
                        unsigned short* combo, short* wt, float* inv,
                        int* epos, float* pooled, unsigned* e_info) {
    __shared__ SmemT sm;
    cg::grid_group grid = cg::this_grid();
    const int tid = threadIdx.x;
    const int GB = gridDim.x;

    {   // zero epos|pooled
        uint4 z = make_uint4(0, 0, 0, 0);
        uint4* zb = (uint4*)epos;
        for (int i = blockIdx.x * NT + tid; i < ZWORDS; i += GB * NT) zb[i] = z;
    }
    grid.sync();

    for (int vb = blockIdx.x; vb < B_PREP; vb += GB) {
        prep_vb(vb, tid, sm, x, ei, eattr, batch, bond, w1f, w2f,
                (unsigned*)xb, combo, wt, epos, e_info, inv, pooled);
        __syncthreads();
    }
    grid.sync();

    const int lane = tid & 63;
    const int wave = tid >> 6;
    const int col  = wave * 32 + (lane & 31);

    for (int l = 0; l < LL; ++l) {
        const unsigned short* cmb = combo + (size_t)l * CPAD * DD;
        for (int grp = blockIdx.x; grp < AGGR_GRP; grp += GB)
            aggr_grp(grp, tid, xb, epos, e_info, cmb, hin);
        grid.sync();

        const short* Wt1 = wt + (size_t)l * DD * DD;
        const short* Wt2 = wt + (size_t)(5 + l) * DD * DD;
        const float sc1 = cg1[l * DD + col] * rsqrtf(cv1[l * DD + col] + BN_EPS);
        const float sh1 = fmaf(cb1[l * DD + col] - cm1[l * DD + col], sc1, cbe1[l * DD + col]);
        const float sc2 = cg2[l * DD + col] * rsqrtf(cv2[l * DD + col] + BN_EPS);
        const float sh2 = fmaf(cb2[l * DD + col] - cm2[l * DD + col], sc2, cbe2[l * DD + col]);
        float* pool_slot = pooled + (size_t)(l + 1) * GG * DD;
        for (int tl = blockIdx.x; tl < CONV_TILES; tl += GB)
            conv_tile(tl, tid, sm, hin, Wt1, Wt2, sc1, sh1, sc2, sh2, batch, xb, pool_slot);
        grid.sync();
    }

    if (blockIdx.x < GG)
        head_blk(blockIdx.x, tid, sm, pooled, inv, fcw, fcb, out);
}

// ===================== fallback multi-kernel path =====================
__launch_bounds__(NT)
__global__ void prep_k(const float* x, const int* ei, const int* eattr, const int* batch,
                       const float* bond, const float* w1f, const float* w2f,
                       unsigned short* xb, unsigned short* combo, short* wt,
                       int* epos, unsigned* e_info, float* inv, float* pooled0) {
    __shared__ SmemT sm;
    prep_vb(blockIdx.x, threadIdx.x, sm, x, ei, eattr, batch, bond, w1f, w2f,
            (unsigned*)xb, combo, wt, epos, e_info, inv, pooled0);
}

__launch_bounds__(NT)
__global__ void aggr_k(const unsigned short* xb, const int* epos, const unsigned* e_info,
                       const unsigned short* cmb, unsigned short* hin) {
    aggr_grp(blockIdx.x, threadIdx.x, xb, epos, e_info, cmb, hin);
}

__launch_bounds__(NT)
__global__ void conv_k(const unsigned short* hin, const short* Wt1, const short* Wt2,
                       const float* b1, const float* g1, const float* be1,
                       const float* m1, const float* v1,
                       const float* b2, const float* g2, const float* be2,
                       const float* m2, const float* v2,
                       const int* batch, unsigned short* outb, float* pool_slot) {
    __shared__ SmemT sm;
    const int tid = threadIdx.x;
    const int col = (tid >> 6) * 32 + (tid & 31);
    const float sc1 = g1[col] * rsqrtf(v1[col] + BN_EPS);
    const float sh1 = fmaf(b1[col] - m1[col], sc1, be1[col]);
    const float sc2 = g2[col] * rsqrtf(v2[col] + BN_EPS);
    const float sh2 = fmaf(b2[col] - m2[col], sc2, be2[col]);
    conv_tile(blockIdx.x, tid, sm, hin, Wt1, Wt2, sc1, sh1, sc2, sh2, batch, outb, pool_slot);
}

__launch_bounds__(64)
__global__ void head_k(const float* pooled, const float* inv, const float* fcw,
                       const float* fcb, float* out) {
    __shared__ SmemT sm;
    head_blk(blockIdx.x, threadIdx.x, sm, pooled, inv, fcw, fcb, out);
}

extern "C" void kernel_launch(void* const* d_in, const int* in_sizes, int n_in,
                              void* d_out, int out_size, void* d_ws, size_t ws_size,
                              hipStream_t stream) {
    const float* x_in    = (const float*)d_in[0];
    const int*   ei      = (const int*)d_in[1];
    const int*   eattr   = (const int*)d_in[2];
    const int*   batch   = (const int*)d_in[3];
    const float* bond    = (const float*)d_in[4];
    const float* conv_w1 = (const float*)d_in[5];
    const float* conv_b1 = (const float*)d_in[6];
    const float* cbg     = (const float*)d_in[7];
    const float* cbb     = (const float*)d_in[8];
    const float* cbm     = (const float*)d_in[9];
    const float* cbv     = (const float*)d_in[10];
    const float* conv_w2 = (const float*)d_in[11];
    const float* conv_b2 = (const float*)d_in[12];
    const float* bg      = (const float*)d_in[13];
    const float* bb      = (const float*)d_in[14];
    const float* bm      = (const float*)d_in[15];
    const float* bv      = (const float*)d_in[16];
    const float* fcw     = (const float*)d_in[17];
    const float* fcb     = (const float*)d_in[18];
    float* out = (float*)d_out;

    char* base = (char*)d_ws;
    size_t o = 0;
    auto carve = [&](size_t bytes) { void* p = base + o; o += (bytes + 15) & ~(size_t)15; return p; };
    unsigned short* xbA    = (unsigned short*)carve((size_t)NN * DD * 2);
    unsigned short* xbB    = (unsigned short*)carve((size_t)NN * DD * 2);
    unsigned short* combo  = (unsigned short*)carve((size_t)LL * CPAD * DD * 2);
    short*          wt     = (short*)carve((size_t)10 * DD * DD * 2);
    float*          inv    = (float*)carve(GG * 4);
    const size_t ZBYTES = (size_t)NN * 4 + (size_t)(LL + 1) * GG * DD * 4;
    int*            epos   = (int*)carve(ZBYTES);
    float*          pooled = (float*)((char*)epos + (size_t)NN * 4);
    unsigned*       e_info = (unsigned*)carve((size_t)NN * ESTRIDE * 4);

    // ---- try cooperative single-kernel; grid sized by runtime occupancy ----
    int dev = 0; hipGetDevice(&dev);
    int coop = 0, ncu = 0, bpcu = 0;
    hipDeviceGetAttribute(&coop, hipDeviceAttributeCooperativeLaunch, dev);
    hipDeviceGetAttribute(&ncu, hipDeviceAttributeMultiprocessorCount, dev);
    hipError_t occ = hipOccupancyMaxActiveBlocksPerMultiprocessor(
        &bpcu, (const void*)gnn_all, NT, 0);
    int grid = (occ == hipSuccess) ? bpcu * ncu : 0;
    if (grid > 2048) grid = 2048;

    bool done = false;
    if (coop && grid >= GG) {
        void* args[] = {
            (void*)&x_in, (void*)&ei, (void*)&eattr, (void*)&batch, (void*)&bond,
            (void*)&conv_w1, (void*)&conv_w2,
            (void*)&conv_b1, (void*)&cbg, (void*)&cbb, (void*)&cbm, (void*)&cbv,
            (void*)&conv_b2, (void*)&bg, (void*)&bb, (void*)&bm, (void*)&bv,
            (void*)&fcw, (void*)&fcb, (void*)&out,
            (void*)&xbA, (void*)&xbB, (void*)&combo, (void*)&wt, (void*)&inv,
            (void*)&epos, (void*)&pooled, (void*)&e_info
        };
        hipError_t err = hipLaunchCooperativeKernel((const void*)gnn_all, dim3(grid),
                                                    dim3(NT), args, 0, stream);
        if (err == hipSuccess) done = true;
        else (void)hipGetLastError();   // clear error state, fall back
    }

    if (!done) {
        // fallback: r11-style multi-kernel chain (proven 423 us)
        hipMemsetAsync(epos, 0, ZBYTES, stream);
        prep_k<<<B_PREP, NT, 0, stream>>>(x_in, ei, eattr, batch, bond, conv_w1, conv_w2,
                                          xbA, combo, wt, epos, e_info, inv, pooled);
        for (int i = 0; i < LL; ++i) {
            aggr_k<<<AGGR_GRP, NT, 0, stream>>>(
                xbA, epos, e_info, combo + (size_t)i * CPAD * DD, xbB);
            conv_k<<<CONV_TILES, NT, 0, stream>>>(
                xbB, wt + (size_t)i * DD * DD, wt + (size_t)(5 + i) * DD * DD,
                conv_b1 + (size_t)i * DD, cbg + (size_t)i * DD, cbb + (size_t)i * DD,
                cbm + (size_t)i * DD, cbv + (size_t)i * DD,
                conv_b2 + (size_t)i * DD, bg + (size_t)i * DD, bb + (size_t)i * DD,
                bm + (size_t)i * DD, bv + (size_t)i * DD,
                batch, xbA, pooled + (size_t)(i + 1) * GG * DD);
        }
        head_k<<<GG, 64, 0, stream>>>(pooled, inv, fcw, fcb, out);
    }
}

// Round 14
// 423.320 us; speedup vs baseline: 2.9778x; 2.9778x over previous
//
#include <hip/hip_runtime.h>

#define NN 50000
#define EE 600000
#define DD 128
#define GG 256
#define LL 5
#define OO 10
#define BN_EPS 1e-5f
#define CPAD 513      // 512 combos + 1 sentinel (-1e30) row per layer
#define ESTRIDE 40    // fixed CSR slots per node (P(deg>40)~1e-9 at lambda=12)
#define SENT (512u << 16)

// prep kernel block-range sizes (scatter first; r11 showed interleave is neutral)
#define B_SCAT  2344                       // ceil(EE/256)
#define B_CVT   3125                       // NN*DD/8 / 256
#define B_COMBO 1283                       // ceil(LL*CPAD*DD / 256)
#define B_WT    160                        // 10 mats x 16 (32x32) tiles
#define B_INV   1
#define B_POOL0 391                        // ceil(NN/128)
#define B_PREP  (B_SCAT + B_CVT + B_COMBO + B_WT + B_INV + B_POOL0)

typedef __attribute__((ext_vector_type(8))) short short8;
typedef __attribute__((ext_vector_type(16))) float float16;

__device__ __forceinline__ unsigned short f2b(float f) {   // fp32 -> bf16 RNE
    unsigned u = __float_as_uint(f);
    unsigned r = u + 0x7FFFu + ((u >> 16) & 1u);
    return (unsigned short)(r >> 16);
}
__device__ __forceinline__ unsigned pk2(float lo, float hi) {
    return (unsigned)f2b(lo) | ((unsigned)f2b(hi) << 16);
}
__device__ __forceinline__ float blo(unsigned u) { return __uint_as_float(u << 16); }
__device__ __forceinline__ float bhi(unsigned u) { return __uint_as_float(u & 0xFFFF0000u); }

// == mega prep: edge-scatter | cvt_x | combo | Wt-transpose | inv | pool0 (all independent) ==
__launch_bounds__(256)
__global__ void prep(const float* __restrict__ x, const int* __restrict__ ei,
                     const int* __restrict__ eattr, const int* __restrict__ batch,
                     const float* __restrict__ bond,
                     const float* __restrict__ w1, const float* __restrict__ w2,
                     unsigned* __restrict__ xb4, unsigned short* __restrict__ combo,
                     short* __restrict__ wt, int* __restrict__ epos,
                     unsigned* __restrict__ e_info,
                     float* __restrict__ inv, float* __restrict__ pooled0) {
    const int bid = blockIdx.x, t = threadIdx.x;
    if (bid < B_SCAT) {
        // scatter edges into fixed-stride CSR. Only dep: epos==0 (memset before launch).
        int e = bid * 256 + t;
        if (e < EE) {
            int dst = ei[EE + e];
            int slot = atomicAdd(&epos[dst], 1);
            if (slot < ESTRIDE) {
                unsigned cidx = (unsigned)eattr[e * 3 + 0] | ((unsigned)eattr[e * 3 + 1] << 3)
                              | ((unsigned)eattr[e * 3 + 2] << 6);
                e_info[dst * ESTRIDE + slot] = (unsigned)ei[e] | (cidx << 16);
            }
        }
    } else if (bid < B_SCAT + B_CVT) {
        // x (fp32) -> xb (bf16), 8 elems/thread
        int gid = (bid - B_SCAT) * 256 + t;
        const float4* xp = (const float4*)(x + (size_t)gid * 8);
        float4 a = xp[0], b = xp[1];
        uint4 o;
        o.x = pk2(a.x, a.y); o.y = pk2(a.z, a.w);
        o.z = pk2(b.x, b.y); o.w = pk2(b.z, b.w);
        ((uint4*)xb4)[gid] = o;
    } else if (bid < B_SCAT + B_CVT + B_COMBO) {
        int e = (bid - B_SCAT - B_CVT) * 256 + t;
        if (e < LL * CPAD * DD) {
            int l = e / (CPAD * DD), rem = e - l * (CPAD * DD);
            int c = rem / DD, d = rem - c * DD;
            float s;
            if (c == 512) s = -1e30f;                     // sentinel row: relu(x+s)==0
            else {
                const float* b_ = bond + (size_t)l * 3 * 8 * DD;
                s = b_[(c & 7) * DD + d] + b_[(8 + ((c >> 3) & 7)) * DD + d]
                  + b_[(16 + (c >> 6)) * DD + d];
            }
            combo[e] = f2b(s);
        }
    } else if (bid < B_SCAT + B_CVT + B_COMBO + B_WT) {
        // coalesced transpose: wt[mat][c][k] = bf16(W[mat][k][c]), 32x32 LDS tiles
        __shared__ float tile[32][33];
        int b = bid - B_SCAT - B_CVT - B_COMBO;
        int mat = b >> 4, tl = b & 15;
        int k0 = (tl >> 2) * 32, c0 = (tl & 3) * 32;
        const float* W = (mat < 5) ? (w1 + (size_t)mat * DD * DD)
                                   : (w2 + (size_t)(mat - 5) * DD * DD);
        int j = t & 31, q = t >> 5;
#pragma unroll
        for (int rr = 0; rr < 4; ++rr) {
            int row = q + rr * 8;
            tile[row][j] = W[(size_t)(k0 + row) * DD + c0 + j];
        }
        __syncthreads();
#pragma unroll
        for (int rr = 0; rr < 4; ++rr) {
            int cr = q + rr * 8;
            wt[(size_t)mat * DD * DD + (size_t)(c0 + cr) * DD + k0 + j] = (short)f2b(tile[j][cr]);
        }
    } else if (bid < B_SCAT + B_CVT + B_COMBO + B_WT + B_INV) {
        // inv[g] via binary search on sorted batch
        __shared__ int sg[GG + 1];
        int g = t, lo = 0, hi = NN;
        while (lo < hi) { int m = (lo + hi) >> 1; if (batch[m] < g) lo = m + 1; else hi = m; }
        sg[g] = lo;
        if (g == 0) sg[GG] = NN;
        __syncthreads();
        inv[g] = 1.0f / fmaxf((float)(sg[g + 1] - sg[g]), 1.0f);
    } else {
        // layer-0 pooling of raw fp32 x: 128 nodes/block, per-graph partials
        int b = bid - (B_SCAT + B_CVT + B_COMBO + B_WT + B_INV);
        int n0 = b * 128;
        __shared__ int sb[128];
        __shared__ float part[4][DD];
        if (t < 128) { int row = n0 + t; sb[t] = (row < NN) ? batch[row] : -1; }
        ((float*)part)[t] = 0.f;
        ((float*)part)[t + 256] = 0.f;
        __syncthreads();
        int gmin = sb[0];
        int col = t & 127, rh = t >> 7;
        float pg[4] = {0.f, 0.f, 0.f, 0.f};
        for (int r = rh; r < 128; r += 2) {
            int s = sb[r];
            float v = (s >= 0) ? x[(size_t)(n0 + r) * DD + col] : 0.f;
            int dg = s - gmin;
#pragma unroll
            for (int jj = 0; jj < 4; ++jj) pg[jj] += (dg == jj) ? v : 0.f;
        }
#pragma unroll
        for (int jj = 0; jj < 4; ++jj)
            if (pg[jj] != 0.f) atomicAdd(&part[jj][col], pg[jj]);
        __syncthreads();
        for (int q2 = t; q2 < 4 * DD; q2 += 256) {
            int jj = q2 >> 7, c2 = q2 & 127;
            float v = part[jj][c2];
            if (v != 0.f && gmin + jj < GG) atomicAdd(&pooled0[(gmin + jj) * DD + c2], v);
        }
    }
}

// ====== CSR aggregation + residual: 16 lanes x 8 feats per edge, 8 edges/iter, masked tail ======
// hin = x + sum relu(x_src + combo); bf16 in/out, fp32 accumulate. No physical sentinels:
// out-of-degree slots are replaced in-register by SENT (combo row 512 = -1e30 -> relu 0).
__launch_bounds__(256)
__global__ void aggr_csr(const unsigned short* __restrict__ xin,
                         const int* __restrict__ epos,
                         const unsigned* __restrict__ e_info,
                         const unsigned short* __restrict__ combo,
                         unsigned short* __restrict__ hin) {
    int node = blockIdx.x * 4 + (threadIdx.x >> 6);
    int lane = threadIdx.x & 63;
    if (node >= NN) return;
    const int base = node * ESTRIDE;
    int deg = epos[node]; if (deg > ESTRIDE) deg = ESTRIDE;
    const int dend = base + deg;
    const int pe   = base + ((deg + 7) & ~7);
    const int eg   = lane >> 4;          // edge sub-group 0..3
    const int f    = (lane & 15) * 8;    // feature offset
    float acc[8];
#pragma unroll
    for (int i = 0; i < 8; ++i) acc[i] = 0.f;

    for (int p = base; p < pe; p += 8) {
        unsigned i0 = e_info[p + eg];         // in-bounds always; garbage masked below
        unsigned i1 = e_info[p + 4 + eg];
        if (p + eg >= dend)     i0 = SENT;
        if (p + 4 + eg >= dend) i1 = SENT;
        uint4 xv0 = *(const uint4*)&xin[(size_t)(i0 & 0xFFFFu) * DD + f];
        uint4 cv0 = *(const uint4*)&combo[(size_t)(i0 >> 16) * DD + f];
        uint4 xv1 = *(const uint4*)&xin[(size_t)(i1 & 0xFFFFu) * DD + f];
        uint4 cv1 = *(const uint4*)&combo[(size_t)(i1 >> 16) * DD + f];
        acc[0] += fmaxf(blo(xv0.x) + blo(cv0.x), 0.f) + fmaxf(blo(xv1.x) + blo(cv1.x), 0.f);
        acc[1] += fmaxf(bhi(xv0.x) + bhi(cv0.x), 0.f) + fmaxf(bhi(xv1.x) + bhi(cv1.x), 0.f);
        acc[2] += fmaxf(blo(xv0.y) + blo(cv0.y), 0.f) + fmaxf(blo(xv1.y) + blo(cv1.y), 0.f);
        acc[3] += fmaxf(bhi(xv0.y) + bhi(cv0.y), 0.f) + fmaxf(bhi(xv1.y) + bhi(cv1.y), 0.f);
        acc[4] += fmaxf(blo(xv0.z) + blo(cv0.z), 0.f) + fmaxf(blo(xv1.z) + blo(cv1.z), 0.f);
        acc[5] += fmaxf(bhi(xv0.z) + bhi(cv0.z), 0.f) + fmaxf(bhi(xv1.z) + bhi(cv1.z), 0.f);
        acc[6] += fmaxf(blo(xv0.w) + blo(cv0.w), 0.f) + fmaxf(blo(xv1.w) + blo(cv1.w), 0.f);
        acc[7] += fmaxf(bhi(xv0.w) + bhi(cv0.w), 0.f) + fmaxf(bhi(xv1.w) + bhi(cv1.w), 0.f);
    }
#pragma unroll
    for (int i = 0; i < 8; ++i) {
        acc[i] += __shfl_xor(acc[i], 16, 64);
        acc[i] += __shfl_xor(acc[i], 32, 64);
    }
    if (lane < 16) {
        uint4 self = *(const uint4*)&xin[(size_t)node * DD + f];
        uint4 o;
        o.x = pk2(acc[0] + blo(self.x), acc[1] + bhi(self.x));
        o.y = pk2(acc[2] + blo(self.y), acc[3] + bhi(self.y));
        o.z = pk2(acc[4] + blo(self.z), acc[5] + bhi(self.z));
        o.w = pk2(acc[6] + blo(self.w), acc[7] + bhi(self.w));
        *(uint4*)&hin[(size_t)node * DD + f] = o;
    }
}

// ========== fused conv + pooling epilogue: relu(bn2(relu(bn1(h@W1+b1))@W2+b2)) ==========
__launch_bounds__(256)
__global__ void conv_fused(const unsigned short* __restrict__ hin,
                           const short* __restrict__ Wt1, const short* __restrict__ Wt2,
                           const float* __restrict__ b1, const float* __restrict__ g1,
                           const float* __restrict__ be1, const float* __restrict__ m1,
                           const float* __restrict__ v1,
                           const float* __restrict__ b2, const float* __restrict__ g2,
                           const float* __restrict__ be2, const float* __restrict__ m2,
                           const float* __restrict__ v2,
                           const int* __restrict__ batch,
                           unsigned short* __restrict__ outb,
                           float* __restrict__ pool_slot) {
    __shared__ short As[64 * 136];
    __shared__ int sbg[64];
    const int tid  = threadIdx.x;
    const int lane = tid & 63;
    const int wave = tid >> 6;
    const int row0 = blockIdx.x * 64;

    const int col   = wave * 32 + (lane & 31);
    const int khalf = (lane >> 5) * 8;
    const int arow  = lane & 31;
    const int rbase = 4 * (lane >> 5);
    const int gmin  = batch[row0];

    short8 bf[8];
#pragma unroll
    for (int ch = 0; ch < 8; ++ch)
        bf[ch] = *(const short8*)&Wt1[col * DD + ch * 16 + khalf];

    const float sc1 = g1[col] * rsqrtf(v1[col] + BN_EPS);
    const float sh1 = fmaf(b1[col] - m1[col], sc1, be1[col]);
    const float sc2 = g2[col] * rsqrtf(v2[col] + BN_EPS);
    const float sh2 = fmaf(b2[col] - m2[col], sc2, be2[col]);

    if (tid < 64) {
        int row = row0 + tid;
        sbg[tid] = (row < NN) ? batch[row] - gmin : -1;
    }
    for (int i = tid; i < 1024; i += 256) {
        int r = i >> 4, c8 = (i & 15) * 8;
        int row = row0 + r;
        uint4 z = make_uint4(0, 0, 0, 0);
        if (row < NN) z = *(const uint4*)&hin[(size_t)row * DD + c8];
        *(uint4*)&As[r * 136 + c8] = z;
    }
    __syncthreads();

    float16 acc0 = {0.f,0.f,0.f,0.f,0.f,0.f,0.f,0.f,0.f,0.f,0.f,0.f,0.f,0.f,0.f,0.f};
    float16 acc1 = acc0;
#pragma unroll
    for (int ch = 0; ch < 8; ++ch) {
        short8 a0 = *(const short8*)&As[(arow     ) * 136 + ch * 16 + khalf];
        short8 a1 = *(const short8*)&As[(32 + arow) * 136 + ch * 16 + khalf];
        acc0 = __builtin_amdgcn_mfma_f32_32x32x16_bf16(a0, bf[ch], acc0, 0, 0, 0);
        acc1 = __builtin_amdgcn_mfma_f32_32x32x16_bf16(a1, bf[ch], acc1, 0, 0, 0);
    }

#pragma unroll
    for (int ch = 0; ch < 8; ++ch)
        bf[ch] = *(const short8*)&Wt2[col * DD + ch * 16 + khalf];

    __syncthreads();
#pragma unroll
    for (int r = 0; r < 16; ++r) {
        int rl = (r & 3) + 8 * (r >> 2) + rbase;
        As[rl * 136 + col]        = (short)f2b(fmaxf(fmaf(acc0[r], sc1, sh1), 0.f));
        As[(32 + rl) * 136 + col] = (short)f2b(fmaxf(fmaf(acc1[r], sc1, sh1), 0.f));
    }
    __syncthreads();

    acc0 = acc1 = float16{0.f,0.f,0.f,0.f,0.f,0.f,0.f,0.f,0.f,0.f,0.f,0.f,0.f,0.f,0.f,0.f};
#pragma unroll
    for (int ch = 0; ch < 8; ++ch) {
        short8 a0 = *(const short8*)&As[(arow     ) * 136 + ch * 16 + khalf];
        short8 a1 = *(const short8*)&As[(32 + arow) * 136 + ch * 16 + khalf];
        acc0 = __builtin_amdgcn_mfma_f32_32x32x16_bf16(a0, bf[ch], acc0, 0, 0, 0);
        acc1 = __builtin_amdgcn_mfma_f32_32x32x16_bf16(a1, bf[ch], acc1, 0, 0, 0);
    }

    float pg0 = 0.f, pg1 = 0.f, pg2 = 0.f, pg3 = 0.f;
#pragma unroll
    for (int r = 0; r < 16; ++r) {
        int rl  = (r & 3) + 8 * (r >> 2) + rbase;
        int row = row0 + rl;
        float v0 = fmaxf(fmaf(acc0[r], sc2, sh2), 0.f);
        float v1_ = fmaxf(fmaf(acc1[r], sc2, sh2), 0.f);
        if (row < NN)      outb[(size_t)row * DD + col]        = f2b(v0);
        if (row + 32 < NN) outb[(size_t)(row + 32) * DD + col] = f2b(v1_);
        int ga = sbg[rl], gb = sbg[rl + 32];
        pg0 += ((ga == 0) ? v0 : 0.f) + ((gb == 0) ? v1_ : 0.f);
        pg1 += ((ga == 1) ? v0 : 0.f) + ((gb == 1) ? v1_ : 0.f);
        pg2 += ((ga == 2) ? v0 : 0.f) + ((gb == 2) ? v1_ : 0.f);
        pg3 += ((ga == 3) ? v0 : 0.f) + ((gb == 3) ? v1_ : 0.f);
    }
    pg0 += __shfl_down(pg0, 32);
    pg1 += __shfl_down(pg1, 32);
    pg2 += __shfl_down(pg2, 32);
    pg3 += __shfl_down(pg3, 32);
    if (lane < 32) {
        if (pg0 != 0.f)                  atomicAdd(&pool_slot[(gmin    ) * DD + col], pg0);
        if (pg1 != 0.f && gmin + 1 < GG) atomicAdd(&pool_slot[(gmin + 1) * DD + col], pg1);
        if (pg2 != 0.f && gmin + 2 < GG) atomicAdd(&pool_slot[(gmin + 2) * DD + col], pg2);
        if (pg3 != 0.f && gmin + 3 < GG) atomicAdd(&pool_slot[(gmin + 3) * DD + col], pg3);
    }
}

// ====== final head: out[g,:] = inv[g]*sum_l pooled_l@fcw_l + sum_l fcb_l ======
__launch_bounds__(64)
__global__ void head(const float* __restrict__ pooled, const float* __restrict__ inv,
                     const float* __restrict__ fcw, const float* __restrict__ fcb,
                     float* __restrict__ out) {
    int g = blockIdx.x, t = threadIdx.x;
    __shared__ float part[LL + 1][OO];
    if (t < (LL + 1) * OO) {
        int l = t / OO, o2 = t - l * OO;
        const float* p = pooled + ((size_t)l * GG + g) * DD;
        const float* w = fcw + (size_t)l * DD * OO + o2;
        float s = 0.f;
        for (int d2 = 0; d2 < DD; ++d2) s = fmaf(p[d2], w[(size_t)d2 * OO], s);
        part[l][o2] = s;
    }
    __syncthreads();
    if (t < OO) {
        float sp = 0.f, sb2 = 0.f;
#pragma unroll
        for (int l = 0; l < LL + 1; ++l) { sp += part[l][t]; sb2 += fcb[l * OO + t]; }
        out[g * OO + t] = sp * inv[g] + sb2;
    }
}

extern "C" void kernel_launch(void* const* d_in, const int* in_sizes, int n_in,
                              void* d_out, int out_size, void* d_ws, size_t ws_size,
                              hipStream_t stream) {
    const float* x_in    = (const float*)d_in[0];
    const int*   ei      = (const int*)d_in[1];
    const int*   eattr   = (const int*)d_in[2];
    const int*   batch   = (const int*)d_in[3];
    const float* bond    = (const float*)d_in[4];
    const float* conv_w1 = (const float*)d_in[5];
    const float* conv_b1 = (const float*)d_in[6];
    const float* cbg     = (const float*)d_in[7];
    const float* cbb     = (const float*)d_in[8];
    const float* cbm     = (const float*)d_in[9];
    const float* cbv     = (const float*)d_in[10];
    const float* conv_w2 = (const float*)d_in[11];
    const float* conv_b2 = (const float*)d_in[12];
    const float* bg      = (const float*)d_in[13];
    const float* bb      = (const float*)d_in[14];
    const float* bm      = (const float*)d_in[15];
    const float* bv      = (const float*)d_in[16];
    const float* fcw     = (const float*)d_in[17];
    const float* fcb     = (const float*)d_in[18];
    float* out = (float*)d_out;

    // ---- workspace carve-up (16B-aligned chunks) ----
    char* base = (char*)d_ws;
    size_t o = 0;
    auto carve = [&](size_t bytes) { void* p = base + o; o += (bytes + 15) & ~(size_t)15; return p; };
    unsigned short* xbA    = (unsigned short*)carve((size_t)NN * DD * 2);
    unsigned short* xbB    = (unsigned short*)carve((size_t)NN * DD * 2);
    unsigned short* combo  = (unsigned short*)carve((size_t)LL * CPAD * DD * 2);
    short*          wt     = (short*)carve((size_t)10 * DD * DD * 2);
    float*          inv    = (float*)carve(GG * 4);
    // contiguous zero-region: epos | pooled[6][G][D]
    const size_t ZBYTES = (size_t)NN * 4 + (size_t)(LL + 1) * GG * DD * 4;
    int*            epos   = (int*)carve(ZBYTES);
    float*          pooled = (float*)((char*)epos + (size_t)NN * 4);
    unsigned*       e_info = (unsigned*)carve((size_t)NN * ESTRIDE * 4);

    hipMemsetAsync(epos, 0, ZBYTES, stream);

    prep<<<B_PREP, 256, 0, stream>>>(x_in, ei, eattr, batch, bond, conv_w1, conv_w2,
                                     (unsigned*)xbA, combo, wt, epos, e_info, inv, pooled);

    const int conv_blocks = (NN + 63) / 64;     // 782
    const int aggr_blocks = (NN + 3) / 4;       // 12500
    unsigned short* xin  = xbA;   // activation buffer (stable across layers)
    unsigned short* xout = xbB;   // hin scratch
    for (int i = 0; i < LL; ++i) {
        aggr_csr<<<aggr_blocks, 256, 0, stream>>>(
            xin, epos, e_info, combo + (size_t)i * CPAD * DD, xout);
        conv_fused<<<conv_blocks, 256, 0, stream>>>(
            xout, wt + (size_t)i * DD * DD, wt + (size_t)(5 + i) * DD * DD,
            conv_b1 + (size_t)i * DD, cbg + (size_t)i * DD, cbb + (size_t)i * DD,
            cbm + (size_t)i * DD, cbv + (size_t)i * DD,
            conv_b2 + (size_t)i * DD, bg + (size_t)i * DD, bb + (size_t)i * DD,
            bm + (size_t)i * DD, bv + (size_t)i * DD,
            batch, xin, pooled + (size_t)(i + 1) * GG * DD);
    }
    head<<<GG, 64, 0, stream>>>(pooled, inv, fcw, fcb, out);
}